// Round 8
// baseline (313.844 us; speedup 1.0000x reference)
//
#include <hip/hip_runtime.h>
#include <hip/hip_bf16.h>
#include <math.h>

typedef _Float16 f16;
typedef f16 f16x8 __attribute__((ext_vector_type(8)));
typedef f16 f16x4 __attribute__((ext_vector_type(4)));
typedef float f32x4 __attribute__((ext_vector_type(4)));

// ============================================================================
// hgemm2: C[M,N] = A[M,K](f16) @ Wt[N,K]^T(f16) + bias(f32)
// Block = 64 rows x NT*64 cols, 256 thr = 4 waves (2m x 2n), wave tile 32x32.
// A-chunk (64 x KCHUNK) is LDS-resident across the whole n-loop -> A global
// traffic = 1x per (m-tile, n-block). B streams global->frags (no LDS): B is
// small, L2/L1-resident, shared by both m-wave-groups. This kills the
// 64-128 MB tile-redundancy traffic of the old per-tile staging design.
// LDS XOR-swizzle on 16B granules -> conflict-free ds_read_b128.
// OUT: 0=f32 store; 1=f16; 2=f16+colsum atomics; 3=f32 specs [B,S,T,80] remap.
// ============================================================================
template<int KCHUNK, int NT, int RELU, int OUT>
__global__ __launch_bounds__(256, 4) void hgemm2(
    const f16* __restrict__ A, const f16* __restrict__ Wt,
    const float* __restrict__ bias, void* __restrict__ Cout, int ldc,
    int K, float* __restrict__ colsum)
{
  __shared__ __align__(16) f16 As[64 * KCHUNK];
  constexpr int GPR = KCHUNK / 8;            // 16B granules per LDS row
  const int tid = threadIdx.x;
  const int wave = tid >> 6, lane = tid & 63;
  const int wm = (wave >> 1) * 32;
  const int wn = (wave & 1) * 32;
  const int m0 = blockIdx.y * 64;
  const int nb0 = blockIdx.x * (NT * 64);
  const int q = lane >> 4, r16 = lane & 15;

  f32x4 acc[NT][2][2];
#pragma unroll
  for (int nt = 0; nt < NT; nt++)
#pragma unroll
    for (int mi = 0; mi < 2; mi++)
#pragma unroll
      for (int ni = 0; ni < 2; ni++) acc[nt][mi][ni] = (f32x4)0.f;

  for (int kc = 0; kc < K; kc += KCHUNK) {
    __syncthreads();   // prior ks-loop LDS reads done before restage
#pragma unroll
    for (int i = 0; i < (64 * GPR) / 256; i++) {
      const int G = i * 256 + tid;
      const int row = G / GPR, g = G % GPR;
      const f16x8 v = *(const f16x8*)(A + (size_t)(m0 + row) * K + kc + g * 8);
      *(f16x8*)((char*)As + (row * GPR + (g ^ (row & (GPR - 1)))) * 16) = v;
    }
    __syncthreads();
    for (int ks = 0; ks < KCHUNK / 32; ks++) {
      f16x8 af[2];
#pragma unroll
      for (int mi = 0; mi < 2; mi++) {
        const int row = wm + mi * 16 + r16;
        af[mi] = *(const f16x8*)((char*)As +
                 (row * GPR + ((ks * 4 + q) ^ (row & (GPR - 1)))) * 16);
      }
#pragma unroll
      for (int nt = 0; nt < NT; nt++) {
        f16x8 bf[2];
#pragma unroll
        for (int ni = 0; ni < 2; ni++) {
          const int n = nb0 + nt * 64 + wn + ni * 16 + r16;
          bf[ni] = *(const f16x8*)(Wt + (size_t)n * K + kc + ks * 32 + q * 8);
        }
#pragma unroll
        for (int mi = 0; mi < 2; mi++)
#pragma unroll
          for (int ni = 0; ni < 2; ni++)
            acc[nt][mi][ni] = __builtin_amdgcn_mfma_f32_16x16x32_f16(
                af[mi], bf[ni], acc[nt][mi][ni], 0, 0, 0);
      }
    }
  }

#pragma unroll
  for (int nt = 0; nt < NT; nt++) {
#pragma unroll
    for (int ni = 0; ni < 2; ni++) {
      const int n = nb0 + nt * 64 + wn + ni * 16 + r16;
      const float bv = bias[n];
      const int s_ = n / 80, o_ = n - s_ * 80;   // OUT==3 only
      float csum = 0.f;
#pragma unroll
      for (int mi = 0; mi < 2; mi++) {
#pragma unroll
        for (int rr = 0; rr < 4; rr++) {
          const int m = m0 + wm + mi * 16 + q * 4 + rr;
          float v = acc[nt][mi][ni][rr] + bv;
          if (RELU) v = fmaxf(v, 0.f);
          if (OUT == 2) csum += v;
          if (OUT == 0)
            ((float*)Cout)[(size_t)m * ldc + n] = v;
          else if (OUT == 3) {
            const int b_ = m >> 10, t_ = m & 1023;
            ((float*)Cout)[((size_t)((b_ * 4 + s_) * 1024 + t_)) * 80 + o_] = v;
          } else
            ((f16*)Cout)[(size_t)m * ldc + n] = (f16)v;
        }
      }
      if (OUT == 2) {
        csum += __shfl_xor(csum, 16);
        csum += __shfl_xor(csum, 32);
        if (q == 0) atomicAdd(&colsum[(m0 >> 10) * 256 + n], csum);
      }
    }
  }
}

// ============================================================================
// Merged prep + video reduce. Blocks [0,7114): weight transposes / audio pad /
// bp copy / colsum zero.  Blocks [7114,7882): conv7x7+mean folded tap-sums.
// ============================================================================
__device__ __forceinline__ void prep_elem(int idx,
    const float* __restrict__ audio,
    const float* __restrict__ w_ae, const float* __restrict__ w_a1,
    const float* __restrict__ w_a2, const float* __restrict__ w_f1,
    const float* __restrict__ w_f2, const float* __restrict__ heads_w,
    const float* __restrict__ heads_b,
    f16* __restrict__ a_h, f16* __restrict__ wae_t, f16* __restrict__ wa1_t,
    f16* __restrict__ wa2_t, f16* __restrict__ wf1_t, f16* __restrict__ wf2_t,
    f16* __restrict__ wh_t, float* __restrict__ bp, float* __restrict__ colsum)
{
  if (idx < 1048576) {  // a_h [8192][128], pad col>=80 with 0
    const int row = idx >> 7, col = idx & 127;
    a_h[idx] = (f16)(col < 80 ? audio[(size_t)row * 80 + col] : 0.f);
    return;
  }
  idx -= 1048576;
  if (idx < 32768) {    // wae_t [256][128]
    const int n = idx >> 7, k = idx & 127;
    wae_t[idx] = (f16)(k < 80 ? w_ae[k * 256 + n] : 0.f);
    return;
  }
  idx -= 32768;
  if (idx < 131072) { const int n = idx >> 8, k = idx & 255; wa1_t[idx] = (f16)w_a1[k * 512 + n]; return; }
  idx -= 131072;
  if (idx < 131072) { const int n = idx >> 9, k = idx & 511; wa2_t[idx] = (f16)w_a2[k * 256 + n]; return; }
  idx -= 131072;
  if (idx < 262144) { const int n = idx >> 9, k = idx & 511; wf1_t[idx] = (f16)w_f1[k * 512 + n]; return; }
  idx -= 262144;
  if (idx < 131072) { const int n = idx >> 9, k = idx & 511; wf2_t[idx] = (f16)w_f2[k * 256 + n]; return; }
  idx -= 131072;
  if (idx < 81920) {    // wh_t [320][256]
    const int n = idx >> 8, d = idx & 255;
    const int s = n / 80, o = n - s * 80;
    wh_t[idx] = (f16)heads_w[(size_t)(s * 256 + d) * 80 + o];
    return;
  }
  idx -= 81920;
  if (idx < 320) { bp[idx] = heads_b[idx]; return; }
  idx -= 320;
  if (idx < 2048) colsum[idx] = 0.f;
}

__global__ __launch_bounds__(256) void prep_video_kernel(
    const float* __restrict__ audio, const float* __restrict__ video,
    const float* __restrict__ w_ae, const float* __restrict__ w_a1,
    const float* __restrict__ w_a2, const float* __restrict__ w_f1,
    const float* __restrict__ w_f2, const float* __restrict__ heads_w,
    const float* __restrict__ heads_b,
    f16* __restrict__ a_h, f16* __restrict__ wae_t, f16* __restrict__ wa1_t,
    f16* __restrict__ wa2_t, f16* __restrict__ wf1_t, f16* __restrict__ wf2_t,
    f16* __restrict__ wh_t, float* __restrict__ bp, float* __restrict__ colsum,
    float* __restrict__ Sg)
{
  const int bid = blockIdx.x;
  if (bid < 7114) {
    prep_elem(bid * 256 + (int)threadIdx.x, audio, w_ae, w_a1, w_a2, w_f1,
              w_f2, heads_w, heads_b, a_h, wae_t, wa1_t, wa2_t, wf1_t, wf2_t,
              wh_t, bp, colsum);
    return;
  }
  // ---- video reduce: one block per (n,c) image ----
  const int img = bid - 7114;
  const float* p = video + (size_t)img * 12544;
  __shared__ float rowS[2][112];
  __shared__ float c0s[112], c1s[112], c109s[112], c110s[112], c111s[112];
  __shared__ float base[14];
  __shared__ float sE[7], sO[7];
  const int t = threadIdx.x;
  if (t < 224) {
    const int r = t >> 1;
    const int par = t & 1;
    const float* rp = p + r * 112 + par;
    float s = 0.f;
#pragma unroll
    for (int i = 0; i < 56; i++) s += rp[2 * i];
    rowS[par][r] = s;
    if (par == 0) { c0s[r] = rp[0]; c110s[r] = rp[110]; }
    else { c1s[r] = rp[0]; c109s[r] = rp[108]; c111s[r] = rp[110]; }
  }
  __syncthreads();
  if (t < 14) {
    const int arr = t >> 1;
    const int rp = t & 1;
    const float* src = (arr == 0) ? rowS[0] : (arr == 1) ? rowS[1] :
                       (arr == 2) ? c0s : (arr == 3) ? c1s :
                       (arr == 4) ? c109s : (arr == 5) ? c110s : c111s;
    float s = 0.f;
    for (int r = rp; r < 112; r += 2) s += src[r];
    base[t] = s;
  }
  __syncthreads();
  if (t < 7) {
    float se, so;
    switch (t) {
      case 0: se = base[2] - base[8] - base[12]; so = base[3] - base[9] - base[13]; break;
      case 1: se = base[0] - base[10];           so = base[1] - base[11];           break;
      case 2: se = base[2] - base[12];           so = base[3] - base[13];           break;
      case 3: se = base[0];                      so = base[1];                      break;
      case 4: se = base[2];                      so = base[3];                      break;
      case 5: se = base[0] - base[4];            so = base[1] - base[5];            break;
      default: se = base[2] - base[6];           so = base[3] - base[7];            break;
    }
    sE[t] = se; sO[t] = so;
  }
  __syncthreads();
  if (t < 49) {
    const int kh = t / 7, kw = t % 7;
    auto ccol = [&](int r) -> float {
      switch (kw) {
        case 0: return rowS[1][r] - c109s[r] - c111s[r];
        case 1: return rowS[0][r] - c110s[r];
        case 2: return rowS[1][r] - c111s[r];
        case 3: return rowS[0][r];
        case 4: return rowS[1][r];
        case 5: return rowS[0][r] - c0s[r];
        default: return rowS[1][r] - c1s[r];
      }
    };
    float v;
    switch (kh) {
      case 0: v = sO[kw] - ccol(109) - ccol(111); break;
      case 1: v = sE[kw] - ccol(110);             break;
      case 2: v = sO[kw] - ccol(111);             break;
      case 3: v = sE[kw];                         break;
      case 4: v = sO[kw];                         break;
      case 5: v = sE[kw] - ccol(0);               break;
      default: v = sO[kw] - ccol(1);              break;
    }
    Sg[(size_t)img * 49 + t] = v;
  }
}

// ============================================================================
// Fused: vpool (49-tap conv+mean) + video FC 64->256.  One block per n (256).
// ============================================================================
__global__ __launch_bounds__(256) void vpool_fc_kernel(
    const float* __restrict__ Sg, const float* __restrict__ conv_w,
    const float* __restrict__ conv_b, const float* __restrict__ w_vfc,
    const float* __restrict__ b_vfc, float* __restrict__ v256)
{
  __shared__ float vp[64];
  const int n = blockIdx.x, t = threadIdx.x;
  if (t < 64) {
    float acc = 0.f;
    const float* s = Sg + (size_t)n * 147;
#pragma unroll 7
    for (int k = 0; k < 147; k++) acc = fmaf(conv_w[t * 147 + k], s[k], acc);
    vp[t] = conv_b[t] + acc * (1.0f / 3136.0f);
  }
  __syncthreads();
  float acc = 0.f;
#pragma unroll
  for (int k = 0; k < 64; k++) acc = fmaf(vp[k], w_vfc[k * 256 + t], acc);
  v256[(size_t)n * 256 + t] = acc + b_vfc[t];
}

// ============================================================================
// LayerNorm(256) f32 -> f16. One wave per row.
// ============================================================================
__global__ __launch_bounds__(256) void layernorm_f16(
    const float* __restrict__ a, const float* __restrict__ g,
    const float* __restrict__ b, f16* __restrict__ out)
{
  const int row = blockIdx.x * 4 + (threadIdx.x >> 6);
  const int lane = threadIdx.x & 63;
  const float4 v = ((const float4*)(a + (size_t)row * 256))[lane];
  float s = v.x + v.y + v.z + v.w;
#pragma unroll
  for (int off = 32; off > 0; off >>= 1) s += __shfl_down(s, off);
  const float mu = __shfl(s, 0) * (1.0f / 256.0f);
  const float dx = v.x - mu, dy = v.y - mu, dz = v.z - mu, dw = v.w - mu;
  float s2 = dx * dx + dy * dy + dz * dz + dw * dw;
#pragma unroll
  for (int off = 32; off > 0; off >>= 1) s2 += __shfl_down(s2, off);
  const float var = __shfl(s2, 0) * (1.0f / 256.0f);
  const float r = rsqrtf(var + 1e-5f);
  const float4 gg = ((const float4*)g)[lane];
  const float4 bb = ((const float4*)b)[lane];
  f16x4 o;
  o[0] = (f16)(dx * r * gg.x + bb.x);
  o[1] = (f16)(dy * r * gg.y + bb.y);
  o[2] = (f16)(dz * r * gg.z + bb.z);
  o[3] = (f16)(dw * r * gg.w + bb.w);
  ((f16x4*)(out + (size_t)row * 256))[lane] = o;
}

// Temporal interp TV=32 -> T=1024, writes f16 into fbuf16 cols [256,512)
__global__ __launch_bounds__(256) void interp_video_f16(
    const float* __restrict__ v256, f16* __restrict__ fbuf)
{
  const int idx = blockIdx.x * 256 + threadIdx.x;
  const int c = idx & 255;
  const int t = (idx >> 8) & 1023;
  const int b = idx >> 18;
  float pos = ((float)t + 0.5f) * 0.03125f - 0.5f;
  pos = fminf(fmaxf(pos, 0.0f), 31.0f);
  const int lo = (int)floorf(pos);
  int hi = lo + 1; if (hi > 31) hi = 31;
  const float w = pos - (float)lo;
  const float vl = v256[(size_t)(b * 32 + lo) * 256 + c];
  const float vh = v256[(size_t)(b * 32 + hi) * 256 + c];
  fbuf[(size_t)(b * 1024 + t) * 512 + 256 + c] = (f16)(vl * (1.0f - w) + vh * w);
}

// ============================================================================
// Tail: energy row-sums (blocks 0..127) + speaker logits (block 128).
// ============================================================================
__global__ __launch_bounds__(256) void tail_kernel(
    const float* __restrict__ specs, const float* __restrict__ colsum,
    const float* __restrict__ w_spk, const float* __restrict__ b_spk,
    float* __restrict__ energy, float* __restrict__ out_logits)
{
  const int bid = blockIdx.x, tid = threadIdx.x;
  if (bid < 128) {
    const int row = bid * 256 + tid;
    const float4* src = (const float4*)(specs + (size_t)row * 80);
    float sum = 0.f;
#pragma unroll
    for (int i = 0; i < 20; i++) {
      const float4 v = src[i];
      sum += v.x + v.y + v.z + v.w;
    }
    energy[row] = sum;
  } else if (tid < 32) {
    const int b = tid >> 2, s = tid & 3;
    const float* cs = colsum + b * 256;
    float acc = 0.f;
#pragma unroll 8
    for (int d = 0; d < 256; d++)
      acc = fmaf(cs[d] * (1.0f / 1024.0f), w_spk[d * 4 + s], acc);
    out_logits[b * 4 + s] = acc + b_spk[s];
  }
}

// ============================================================================
// Waveforms: JAX partitionable threefry2x32 (key=[0,1234]) + XLA erfinv
// ============================================================================
__device__ __forceinline__ unsigned rotl32(unsigned x, int d) {
  return (x << d) | (x >> (32 - d));
}

__device__ __forceinline__ float erfinv_xla(float x) {
  float w = -log1pf(-x * x);
  float p;
  if (w < 5.0f) {
    w = w - 2.5f;
    p = 2.81022636e-08f;
    p = fmaf(p, w, 3.43273939e-07f);
    p = fmaf(p, w, -3.5233877e-06f);
    p = fmaf(p, w, -4.39150654e-06f);
    p = fmaf(p, w, 0.00021858087f);
    p = fmaf(p, w, -0.00125372503f);
    p = fmaf(p, w, -0.00417768164f);
    p = fmaf(p, w, 0.246640727f);
    p = fmaf(p, w, 1.50140941f);
  } else {
    w = sqrtf(w) - 3.0f;
    p = -0.000200214257f;
    p = fmaf(p, w, 0.000100950558f);
    p = fmaf(p, w, 0.00134934322f);
    p = fmaf(p, w, -0.00367342844f);
    p = fmaf(p, w, 0.00573950773f);
    p = fmaf(p, w, -0.0076224613f);
    p = fmaf(p, w, 0.00943887047f);
    p = fmaf(p, w, 1.00167406f);
    p = fmaf(p, w, 2.83297682f);
  }
  return p * x;
}

__global__ __launch_bounds__(256) void waveform_kernel(
    const float* __restrict__ energy, float* __restrict__ out)
{
  const unsigned n = blockIdx.x * 256 + threadIdx.x;   // [0, 5242880)
  const unsigned ks0 = 0u, ks1 = 1234u;
  const unsigned ks2 = 0x1BD11BDAu ^ ks0 ^ ks1;
  unsigned x0 = ks0;
  unsigned x1 = n + ks1;
#define TF_R4(a, b, c, d)                        \
  x0 += x1; x1 = rotl32(x1, a); x1 ^= x0;        \
  x0 += x1; x1 = rotl32(x1, b); x1 ^= x0;        \
  x0 += x1; x1 = rotl32(x1, c); x1 ^= x0;        \
  x0 += x1; x1 = rotl32(x1, d); x1 ^= x0;
  TF_R4(13, 15, 26, 6)  x0 += ks1; x1 += ks2 + 1u;
  TF_R4(17, 29, 16, 24) x0 += ks2; x1 += ks0 + 2u;
  TF_R4(13, 15, 26, 6)  x0 += ks0; x1 += ks1 + 3u;
  TF_R4(17, 29, 16, 24) x0 += ks1; x1 += ks2 + 4u;
  TF_R4(13, 15, 26, 6)  x0 += ks2; x1 += ks0 + 5u;
#undef TF_R4
  const unsigned bits = x0 ^ x1;
  const float f = __uint_as_float((bits >> 9) | 0x3f800000u) - 1.0f;
  const float minv = -0.99999994f;
  const float u = fmaxf(minv, fmaf(f, 2.0f, minv));
  const float noise = 1.41421354f * erfinv_xla(u) * 0.1f;
  const unsigned i = n % 163840u;
  const unsigned bs = n / 163840u;
  float pos = ((float)i + 0.5f) * 0.00625f - 0.5f;
  pos = fminf(fmaxf(pos, 0.0f), 1023.0f);
  const int lo = (int)floorf(pos);
  int hi = lo + 1; if (hi > 1023) hi = 1023;
  const float w = pos - (float)lo;
  const float* e = energy + (size_t)bs * 1024;
  const float ev = e[lo] * (1.0f - w) + e[hi] * w;
  out[n] = noise * fmaf(ev, 0.5f, 0.5f);
}

// ============================================================================
extern "C" void kernel_launch(void* const* d_in, const int* in_sizes, int n_in,
                              void* d_out, int out_size, void* d_ws, size_t ws_size,
                              hipStream_t stream)
{
  (void)in_sizes; (void)n_in; (void)out_size; (void)ws_size;
  const float* audio   = (const float*)d_in[0];
  const float* video   = (const float*)d_in[1];
  const float* w_ae    = (const float*)d_in[2];
  const float* b_ae    = (const float*)d_in[3];
  const float* ln_g    = (const float*)d_in[4];
  const float* ln_b    = (const float*)d_in[5];
  const float* w_a1    = (const float*)d_in[6];
  const float* b_a1    = (const float*)d_in[7];
  const float* w_a2    = (const float*)d_in[8];
  const float* b_a2    = (const float*)d_in[9];
  const float* conv_w  = (const float*)d_in[10];
  const float* conv_b  = (const float*)d_in[11];
  const float* w_vfc   = (const float*)d_in[12];
  const float* b_vfc   = (const float*)d_in[13];
  const float* w_f1    = (const float*)d_in[14];
  const float* b_f1    = (const float*)d_in[15];
  const float* w_f2    = (const float*)d_in[16];
  const float* b_f2    = (const float*)d_in[17];
  const float* heads_w = (const float*)d_in[18];
  const float* heads_b = (const float*)d_in[19];
  const float* w_spk   = (const float*)d_in[20];
  const float* b_spk   = (const float*)d_in[21];

  float* ws = (float*)d_ws;
  float* a0     = ws;                 // 2,097,152 f32
  float* colsum = ws + 2097152;       // 2,048
  float* Sg     = ws + 2099200;       // 37,632
  float* v256   = ws + 2136832;       // 65,536
  float* energy = ws + 2202368;       // 32,768
  float* bp     = ws + 2235136;       // 320 (+pad to 2235456)
  f16* fh = (f16*)(ws + 2235456);
  f16* a1     = fh;                   // 2,097,152 f16
  f16* h16    = a1 + 2097152;         // 4,194,304
  f16* fbuf16 = h16 + 4194304;        // 4,194,304
  f16* a_h    = fbuf16 + 4194304;     // 1,048,576
  f16* wae_t  = a_h + 1048576;        //    32,768
  f16* wa1_t  = wae_t + 32768;        //   131,072
  f16* wa2_t  = wa1_t + 131072;       //   131,072
  f16* wf1_t  = wa2_t + 131072;       //   262,144
  f16* wf2_t  = wf1_t + 262144;       //   131,072
  f16* wh_t   = wf2_t + 131072;       //    81,920

  float* out_wave   = (float*)d_out;           // 5,242,880
  float* out_specs  = out_wave + 5242880;      // 2,621,440
  float* out_logits = out_specs + 2621440;     // 32

  // ---- prep (weights/audio/colsum/bp) + video reduce, one dispatch ----
  prep_video_kernel<<<7882, 256, 0, stream>>>(
      audio, video, w_ae, w_a1, w_a2, w_f1, w_f2, heads_w, heads_b,
      a_h, wae_t, wa1_t, wa2_t, wf1_t, wf2_t, wh_t, bp, colsum, Sg);

  // ---- video pooled FC ----
  vpool_fc_kernel<<<256, 256, 0, stream>>>(Sg, conv_w, conv_b, w_vfc, b_vfc, v256);

  // ---- audio branch ----
  hgemm2<128, 2, 0, 0><<<dim3(2, 128), 256, 0, stream>>>(
      a_h, wae_t, b_ae, a0, 256, 128, nullptr);
  layernorm_f16<<<2048, 256, 0, stream>>>(a0, ln_g, ln_b, a1);
  hgemm2<256, 2, 1, 1><<<dim3(4, 128), 256, 0, stream>>>(
      a1, wa1_t, b_a1, h16, 512, 256, nullptr);
  hgemm2<256, 2, 0, 1><<<dim3(2, 128), 256, 0, stream>>>(
      h16, wa2_t, b_a2, fbuf16, 512, 512, nullptr);
  interp_video_f16<<<8192, 256, 0, stream>>>(v256, fbuf16);

  // ---- fusion ----
  hgemm2<256, 2, 1, 1><<<dim3(4, 128), 256, 0, stream>>>(
      fbuf16, wf1_t, b_f1, h16, 512, 512, nullptr);
  hgemm2<256, 2, 0, 2><<<dim3(2, 128), 256, 0, stream>>>(
      h16, wf2_t, b_f2, a1, 256, 512, colsum);

  // ---- heads -> specs [B,S,T,80] ----
  hgemm2<256, 1, 0, 3><<<dim3(5, 128), 256, 0, stream>>>(
      a1, wh_t, bp, out_specs, 0, 256, nullptr);

  // ---- energy + speaker logits ----
  tail_kernel<<<129, 256, 0, stream>>>(out_specs, colsum, w_spk, b_spk,
                                       energy, out_logits);

  // ---- waveforms ----
  waveform_kernel<<<20480, 256, 0, stream>>>(energy, out_wave);
}